// Round 16
// baseline (131.407 us; speedup 1.0000x reference)
//
#include <hip/hip_runtime.h>
#include <math.h>

#define B_   256
#define IN_  512
#define C_   4
#define M_   6
#define K_   64
#define S1_  255
#define S2_  63

#define NBLK1 (C_ * S1_)                 // 1020
#define NBLK2 (C_ * S2_)                 // 252
#define NBLK3 (C_)                       // 4
#define NBLK_ALL (NBLK1 + NBLK2 + NBLK3) // 1276

#define NPF   1020                        // prefetch blocks in route launch
#define UPB1  4080                        // update1 blocks total (4/tile)
#define UPB1H (UPB1 / 2)                  // half: 2040
#define UPB2  504                         // update2 blocks (2/tile)

#define LMIN_ (-6.906754778648554f)
#define LMAX_ ( 6.906754778648554f)
#define LR_   0.001f
#define WCLIP_ 5.0f

typedef float v4f __attribute__((ext_vector_type(4)));

__device__ __forceinline__ float clampf(float v, float lo, float hi) {
    return fminf(fmaxf(v, lo), hi);
}

// One-time prep: xT[i][b], l0[b][i], l0T[i][b]; bias rows of out1/out2.
__global__ __launch_bounds__(256) void prep_kernel(const float* __restrict__ x,
                                                   const float* __restrict__ bias1,
                                                   const float* __restrict__ bias2,
                                                   float* __restrict__ xT,
                                                   float* __restrict__ l0,
                                                   float* __restrict__ l0T,
                                                   float* __restrict__ out1T,
                                                   float* __restrict__ out1RM,
                                                   float* __restrict__ out2T,
                                                   float* __restrict__ out2RM) {
    __shared__ float tx_[32][33];
    __shared__ float tl_[32][33];
    const int i0 = (blockIdx.x & 15) * 32;
    const int b0 = (blockIdx.x >> 4) * 32;
    const int tx = threadIdx.x & 31;
    const int ty = threadIdx.x >> 5;
#pragma unroll
    for (int r = 0; r < 4; ++r) {
        int bb = b0 + ty + 8 * r;
        int ii = i0 + tx;
        float xv = x[(size_t)bb * IN_ + ii];
        float xc = clampf(xv, 0.001f, 0.999f);
        float lv = (ii == 0) ? 0.0f : logf(xc / (1.0f - xc));
        l0[(size_t)bb * IN_ + ii] = lv;
        tx_[ty + 8 * r][tx] = xv;
        tl_[ty + 8 * r][tx] = lv;
    }
    __syncthreads();
#pragma unroll
    for (int r = 0; r < 4; ++r) {
        int ii = i0 + ty + 8 * r;
        int bb = b0 + tx;
        xT[(size_t)ii * B_ + bb]  = tx_[tx][ty + 8 * r];
        l0T[(size_t)ii * B_ + bb] = tl_[tx][ty + 8 * r];
    }
    int gid = blockIdx.x * 256 + threadIdx.x;
    if (gid < C_ * B_) {
        int c = gid >> 8, b = gid & 255;
        float b1 = bias1[c], b2 = bias2[c];
        out1T[((size_t)c * (S1_ + 1)) * B_ + b] = b1;
        out1RM[((size_t)c * B_ + b) * (S1_ + 1)] = b1;
        out2T[((size_t)c * (S2_ + 1)) * B_ + b] = b2;
        out2RM[((size_t)c * B_ + b) * (S2_ + 1)] = b2;
    }
}

// Routing (blocks [0,638)): 2 tiles/block, 4 waves x 128-k quarters (proven).
// Prefetch (blocks [638, 638+NPF)): stream w1/w2/w3 into L3 while route's
// VALU work runs -> dotfin1's w1 read becomes an L3 hit.
__global__ __launch_bounds__(256) void route_pf_kernel(
    const float* __restrict__ xT,       // [IN][B]
    const float* __restrict__ cmaps1,
    const float* __restrict__ cmaps2,
    const float* __restrict__ cmaps3,
    int* __restrict__ idx_buf,          // [NBLK_ALL][B]
    const float* __restrict__ w1,
    const float* __restrict__ w2,
    const float* __restrict__ w3)
{
    __shared__ float sacc[3][2][M_][B_];   // 36 KB
    if ((int)blockIdx.x >= NBLK_ALL / 2) {
        // ---- prefetch family: read-only, sink via asm ----
        const int pb = blockIdx.x - NBLK_ALL / 2;
        const int t  = pb * 256 + threadIdx.x;
        const int stride = NPF * 256;
        const int n1 = C_ * S1_ * K_ * IN_ / 4;        // 8355840 f4
        const int n2 = C_ * S2_ * K_ * (S1_ + 1) / 4;  // 1032192 f4
        const int n3 = C_ * 1 * K_ * (S2_ + 1) / 4;    // 4096 f4
        const float4* w1v = (const float4*)w1;
        const float4* w2v = (const float4*)w2;
        const float4* w3v = (const float4*)w3;
        float s = 0.0f;
        for (int i = t; i < n1; i += stride) { float4 v = w1v[i]; s += v.x + v.y + v.z + v.w; }
        for (int i = t; i < n2; i += stride) { float4 v = w2v[i]; s += v.x + v.y + v.z + v.w; }
        for (int i = t; i < n3; i += stride) { float4 v = w3v[i]; s += v.x + v.y + v.z + v.w; }
        asm volatile("" :: "v"(s));
        return;
    }

    const int wv   = __builtin_amdgcn_readfirstlane(threadIdx.x >> 6);
    const int lane = threadIdx.x & 63;
    const int t0   = blockIdx.x * 2;

    const float* cmp[2];
#pragma unroll
    for (int u = 0; u < 2; ++u) {
        int bid = t0 + u;
        if (bid < NBLK1)              cmp[u] = cmaps1 + (size_t)bid * M_ * IN_;
        else if (bid < NBLK1 + NBLK2) cmp[u] = cmaps2 + (size_t)(bid - NBLK1) * M_ * IN_;
        else                          cmp[u] = cmaps3 + (size_t)(bid - NBLK1 - NBLK2) * M_ * IN_;
    }

    float acc[2][4][M_];
#pragma unroll
    for (int u = 0; u < 2; ++u)
#pragma unroll
        for (int jb = 0; jb < 4; ++jb)
#pragma unroll
            for (int m = 0; m < M_; ++m) acc[u][jb][m] = 0.0f;

    const int kw = wv * 128;
    for (int k0 = kw; k0 < kw + 128; k0 += 8) {
        float xv[8][4];
#pragma unroll
        for (int j = 0; j < 8; ++j)
#pragma unroll
            for (int jb = 0; jb < 4; ++jb)
                xv[j][jb] = xT[(size_t)(k0 + j) * B_ + 64 * jb + lane];
#pragma unroll
        for (int j = 0; j < 8; ++j)
#pragma unroll
            for (int u = 0; u < 2; ++u)
#pragma unroll
                for (int m = 0; m < M_; ++m) {
                    float cv = cmp[u][(size_t)m * IN_ + k0 + j];
#pragma unroll
                    for (int jb = 0; jb < 4; ++jb)
                        acc[u][jb][m] = fmaf(cv, xv[j][jb], acc[u][jb][m]);
                }
    }

    if (wv > 0) {
#pragma unroll
        for (int u = 0; u < 2; ++u)
#pragma unroll
            for (int jb = 0; jb < 4; ++jb)
#pragma unroll
                for (int m = 0; m < M_; ++m)
                    sacc[wv - 1][u][m][64 * jb + lane] = acc[u][jb][m];
    }
    __syncthreads();
    if (wv == 0) {
#pragma unroll
        for (int u = 0; u < 2; ++u)
#pragma unroll
            for (int jb = 0; jb < 4; ++jb) {
                int b = 64 * jb + lane;
                int myidx = 0;
#pragma unroll
                for (int m = 0; m < M_; ++m) {
                    float t = acc[u][jb][m] + sacc[0][u][m][b] + sacc[1][u][m][b] + sacc[2][u][m][b];
                    myidx |= (t > 0.0f) ? (1 << m) : 0;
                }
                idx_buf[(size_t)(t0 + u) * B_ + b] = myidx;
            }
    }
}

// ---- fused dot+fin per tile: 512 threads = 2 k-halves x 256 b ----
// Register-prefetch double-buffered staging (proven round 15).
template<int DIN>
__device__ __forceinline__ void dotfin_body(
    int tile,
    const float* __restrict__ lgT, long lgT_sc,
    const float* __restrict__ w,
    const int* __restrict__ idx_buf,
    const int* __restrict__ target,
    float* __restrict__ onextT,
    float* __restrict__ onextRM,
    int* __restrict__ win_g,
    float* __restrict__ dw_g,
    int S,
    float* wl, float* part_s, float* diff_s, int* win_s)
{
    constexpr int HALF = DIN / 2;
    constexpr int NR   = HALF / 64;
    const int c   = tile / S;
    const int s   = tile - c * S;
    const int tid = threadIdx.x;
    const int kh  = __builtin_amdgcn_readfirstlane(tid >> 8);
    const int b   = tid & 255;

    if (tid < K_) win_s[tid] = -1;
    const int myrow = idx_buf[(size_t)tile * B_ + b];

    const float* wp  = w + (size_t)tile * K_ * DIN + kh * HALF;
    float*       dst = wl + kh * (K_ * 65);

    int rrow[4], rq[4];
    float4 pre[4];
#pragma unroll
    for (int j = 0; j < 4; ++j) {
        int f   = b + 256 * j;
        rrow[j] = f >> 4;
        rq[j]   = (f & 15) << 2;
        pre[j]  = *(const float4*)(wp + (size_t)rrow[j] * DIN + rq[j]);
    }

    float dot = 0.0f;
#pragma unroll
    for (int r = 0; r < NR; ++r) {
#pragma unroll
        for (int j = 0; j < 4; ++j) {
            dst[rrow[j] * 65 + rq[j] + 0] = pre[j].x;
            dst[rrow[j] * 65 + rq[j] + 1] = pre[j].y;
            dst[rrow[j] * 65 + rq[j] + 2] = pre[j].z;
            dst[rrow[j] * 65 + rq[j] + 3] = pre[j].w;
        }
        if (r + 1 < NR) {
            const float* src = wp + (r + 1) * 64;
#pragma unroll
            for (int j = 0; j < 4; ++j)
                pre[j] = *(const float4*)(src + (size_t)rrow[j] * DIN + rq[j]);
        }
        __syncthreads();
        const float* lgp = lgT + (size_t)c * lgT_sc + (size_t)(kh * HALF + r * 64) * B_ + b;
        const float* wr  = dst + myrow * 65;
        for (int kk = 0; kk < 64; kk += 8) {
            float lv[8];
#pragma unroll
            for (int t = 0; t < 8; ++t) lv[t] = lgp[(size_t)(kk + t) * B_];
#pragma unroll
            for (int t = 0; t < 8; ++t) dot = fmaf(wr[kk + t], lv[t], dot);
        }
        __syncthreads();
    }
    if (kh == 1) part_s[b] = dot;
    __syncthreads();
    if (kh == 0) {
        float total = dot + part_s[b];
        float outv = clampf(total, LMIN_, LMAX_);
        onextT[((size_t)c * (S + 1) + (s + 1)) * B_ + b] = outv;
        onextRM[((size_t)c * B_ + b) * (size_t)(S + 1) + (s + 1)] = outv;
        float tg = (target[b] == c) ? 1.0f : 0.0f;
        diff_s[b] = 1.0f / (1.0f + expf(-outv)) - tg;
        atomicMax(&win_s[myrow], b);
    }
    __syncthreads();
    if (tid < K_) {
        int bw = win_s[tid];
        win_g[(size_t)tile * K_ + tid] = bw;
        dw_g[(size_t)tile * K_ + tid]  = (bw >= 0) ? LR_ * diff_s[bw] : 0.0f;
    }
}

// stream update, 512 threads, batched loads (proven round 15).
template<int DIN>
__device__ __forceinline__ void update_body(
    int ub,
    const float* __restrict__ w,
    const float* __restrict__ lgRM, long lg_sc,
    const int* __restrict__ win_g,
    const float* __restrict__ dw_g,
    float* __restrict__ nw,
    int SK)
{
    constexpr int QPR = DIN / 4;
    constexpr int QSH = (DIN == 512) ? 7 : 6;
    const int base = ub * 2048 + threadIdx.x;
    int row[4], col[4], bw[4];
    float d[4];
    float4 wv[4], lv[4];
#pragma unroll
    for (int j = 0; j < 4; ++j) {
        int Q  = base + j * 512;
        row[j] = Q >> QSH;
        col[j] = (Q & (QPR - 1)) << 2;
        wv[j]  = *(const float4*)(w + (size_t)row[j] * DIN + col[j]);
    }
#pragma unroll
    for (int j = 0; j < 4; ++j) {
        bw[j] = win_g[row[j]];
        d[j]  = dw_g[row[j]];
    }
#pragma unroll
    for (int j = 0; j < 4; ++j) {
        int safe = bw[j] < 0 ? 0 : bw[j];
        int cc   = row[j] / SK;
        lv[j] = *(const float4*)(lgRM + (size_t)cc * lg_sc + (size_t)safe * DIN + col[j]);
    }
#pragma unroll
    for (int j = 0; j < 4; ++j) {
        if (bw[j] >= 0) {
            wv[j].x = clampf(wv[j].x - d[j] * lv[j].x, -WCLIP_, WCLIP_);
            wv[j].y = clampf(wv[j].y - d[j] * lv[j].y, -WCLIP_, WCLIP_);
            wv[j].z = clampf(wv[j].z - d[j] * lv[j].z, -WCLIP_, WCLIP_);
            wv[j].w = clampf(wv[j].w - d[j] * lv[j].w, -WCLIP_, WCLIP_);
        }
        v4f o = {wv[j].x, wv[j].y, wv[j].z, wv[j].w};
        __builtin_nontemporal_store(o, (v4f*)(nw + (size_t)row[j] * DIN + col[j]));
    }
}

// Layer-1 dot+fin standalone.
__global__ __launch_bounds__(512) void dotfin1_kernel(
    const float* __restrict__ l0T,
    const float* __restrict__ w1,
    const int* __restrict__ idx1,
    const int* __restrict__ target,
    float* __restrict__ out1T, float* __restrict__ out1RM,
    int* __restrict__ win1, float* __restrict__ dw1)
{
    __shared__ float wl[2 * K_ * 65];
    __shared__ float part_s[B_];
    __shared__ float diff_s[B_];
    __shared__ int   win_s[K_];
    dotfin_body<512>(blockIdx.x, l0T, 0L, w1, idx1, target,
                     out1T, out1RM, win1, dw1, S1_, wl, part_s, diff_s, win_s);
}

// mix2: [0,NBLK2) layer-2 dot+fin; [NBLK2, NBLK2+UPB1H) update1 first half.
__global__ __launch_bounds__(512) void mix2_kernel(
    const float* __restrict__ out1T,
    const float* __restrict__ w2,
    const int* __restrict__ idx2,
    const int* __restrict__ target,
    float* __restrict__ out2T, float* __restrict__ out2RM,
    int* __restrict__ win2, float* __restrict__ dw2,
    const float* __restrict__ w1,
    const float* __restrict__ l0,
    const int* __restrict__ win1, const float* __restrict__ dw1,
    float* __restrict__ nw1)
{
    __shared__ float wl[2 * K_ * 65];
    __shared__ float part_s[B_];
    __shared__ float diff_s[B_];
    __shared__ int   win_s[K_];
    if ((int)blockIdx.x < NBLK2)
        dotfin_body<256>(blockIdx.x, out1T, (long)(S1_ + 1) * B_, w2, idx2, target,
                         out2T, out2RM, win2, dw2, S2_,
                         wl, part_s, diff_s, win_s);
    else
        update_body<512>(blockIdx.x - NBLK2, w1, l0, 0L, win1, dw1, nw1, S1_ * K_);
}

// layer-3 full fusion (proven).
__device__ __forceinline__ void dotfinup3_body(
    int c,
    const float* __restrict__ lgT, long lgT_sc,
    const float* __restrict__ lgRM, long lg_sc,
    const float* __restrict__ w3,
    const int* __restrict__ idx3,
    const int* __restrict__ target,
    float* __restrict__ nw3,
    float* __restrict__ logits,
    float* wl, float* part_s, float* diff_s, float* dw_s, int* win_s)
{
    const int tid = threadIdx.x;
    const int kh  = __builtin_amdgcn_readfirstlane(tid >> 8);
    const int b   = tid & 255;
    if (tid < K_) win_s[tid] = -1;
    const int myrow = idx3[(size_t)c * B_ + b];

    const float* wp  = w3 + (size_t)c * K_ * 64 + kh * 32;
    float*       dst = wl + kh * (K_ * 33);
#pragma unroll
    for (int j = 0; j < 2; ++j) {
        int f   = b + 256 * j;
        int row = f >> 3;
        int q   = (f & 7) << 2;
        float4 v = *(const float4*)(wp + (size_t)row * 64 + q);
        dst[row * 33 + q + 0] = v.x;
        dst[row * 33 + q + 1] = v.y;
        dst[row * 33 + q + 2] = v.z;
        dst[row * 33 + q + 3] = v.w;
    }
    __syncthreads();
    const float* lgp = lgT + (size_t)c * lgT_sc + (size_t)(kh * 32) * B_ + b;
    const float* wr  = dst + myrow * 33;
    float dot = 0.0f;
    for (int kk = 0; kk < 32; kk += 8) {
        float lv[8];
#pragma unroll
        for (int t = 0; t < 8; ++t) lv[t] = lgp[(size_t)(kk + t) * B_];
#pragma unroll
        for (int t = 0; t < 8; ++t) dot = fmaf(wr[kk + t], lv[t], dot);
    }
    if (kh == 1) part_s[b] = dot;
    __syncthreads();
    if (kh == 0) {
        float total = dot + part_s[b];
        float outv = clampf(total, LMIN_, LMAX_);
        logits[(size_t)b * C_ + c] = outv;
        float tg = (target[b] == c) ? 1.0f : 0.0f;
        diff_s[b] = 1.0f / (1.0f + expf(-outv)) - tg;
        atomicMax(&win_s[myrow], b);
    }
    __syncthreads();
    if (tid < K_) dw_s[tid] = (win_s[tid] >= 0) ? LR_ * diff_s[win_s[tid]] : 0.0f;
    __syncthreads();

    const float* lgc = lgRM + (size_t)c * lg_sc;
    float* nwp = nw3 + (size_t)c * K_ * 64;
#pragma unroll
    for (int j = 0; j < 2; ++j) {
        int Q   = tid + 512 * j;
        int row = Q >> 4;
        int col = (Q & 15) << 2;
        const float* wsrc = wl + (col >> 5) * (K_ * 33) + row * 33 + (col & 31);
        float4 wv = {wsrc[0], wsrc[1], wsrc[2], wsrc[3]};
        int bw = win_s[row];
        if (bw >= 0) {
            float d = dw_s[row];
            const float4 lv = *(const float4*)(lgc + (size_t)bw * 64 + col);
            wv.x = clampf(wv.x - d * lv.x, -WCLIP_, WCLIP_);
            wv.y = clampf(wv.y - d * lv.y, -WCLIP_, WCLIP_);
            wv.z = clampf(wv.z - d * lv.z, -WCLIP_, WCLIP_);
            wv.w = clampf(wv.w - d * lv.w, -WCLIP_, WCLIP_);
        }
        v4f o = {wv.x, wv.y, wv.z, wv.w};
        __builtin_nontemporal_store(o, (v4f*)(nwp + (size_t)row * 64 + col));
    }
}

// mix3: [0,4) layer-3 fusion; [4,4+UPB2) update2; [4+UPB2, ...) update1 2nd half.
__global__ __launch_bounds__(512) void mix3_kernel(
    const float* __restrict__ out2T,
    const float* __restrict__ out2RM,
    const float* __restrict__ w3,
    const int* __restrict__ idx3,
    const int* __restrict__ target,
    float* __restrict__ nw3,
    float* __restrict__ logits,
    const float* __restrict__ w2,
    const float* __restrict__ out1RM,
    const int* __restrict__ win2, const float* __restrict__ dw2,
    float* __restrict__ nw2,
    const float* __restrict__ w1,
    const float* __restrict__ l0,
    const int* __restrict__ win1, const float* __restrict__ dw1,
    float* __restrict__ nw1)
{
    __shared__ float wl[2 * K_ * 33];
    __shared__ float part_s[B_];
    __shared__ float diff_s[B_];
    __shared__ float dw_s[K_];
    __shared__ int   win_s[K_];
    if ((int)blockIdx.x < NBLK3)
        dotfinup3_body(blockIdx.x, out2T, (long)(S2_ + 1) * B_,
                       out2RM, (long)B_ * (S2_ + 1), w3, idx3, target,
                       nw3, logits, wl, part_s, diff_s, dw_s, win_s);
    else if ((int)blockIdx.x < NBLK3 + UPB2)
        update_body<256>(blockIdx.x - NBLK3, w2, out1RM, (long)B_ * (S1_ + 1),
                         win2, dw2, nw2, S2_ * K_);
    else
        update_body<512>(blockIdx.x - (NBLK3 + UPB2) + UPB1H, w1, l0, 0L,
                         win1, dw1, nw1, S1_ * K_);
}

extern "C" void kernel_launch(void* const* d_in, const int* in_sizes, int n_in,
                              void* d_out, int out_size, void* d_ws, size_t ws_size,
                              hipStream_t stream) {
    const float* x      = (const float*)d_in[0];
    const int*   target = (const int*)  d_in[1];
    const float* cmaps1 = (const float*)d_in[2];
    const float* w1     = (const float*)d_in[3];
    const float* bias1  = (const float*)d_in[4];
    const float* cmaps2 = (const float*)d_in[5];
    const float* w2     = (const float*)d_in[6];
    const float* bias2  = (const float*)d_in[7];
    const float* cmaps3 = (const float*)d_in[8];
    const float* w3     = (const float*)d_in[9];
    float* out = (float*)d_out;

    float* xT      = (float*)d_ws;
    float* l0      = xT     + (size_t)IN_ * B_;
    float* l0T     = l0     + (size_t)B_ * IN_;
    float* out1T   = l0T    + (size_t)IN_ * B_;
    float* out1RM  = out1T  + (size_t)C_ * (S1_ + 1) * B_;
    float* out2T   = out1RM + (size_t)C_ * B_ * (S1_ + 1);
    float* out2RM  = out2T  + (size_t)C_ * (S2_ + 1) * B_;
    float* dw_g    = out2RM + (size_t)C_ * B_ * (S2_ + 1);
    int*   win_g   = (int*)(dw_g + (size_t)(NBLK1 + NBLK2) * K_);
    int*   idx_buf = (int*)(win_g + (size_t)(NBLK1 + NBLK2) * K_);

    float* logits = out;
    float* nw1 = out + (size_t)B_ * C_;
    float* nw2 = nw1 + (size_t)C_ * S1_ * K_ * IN_;
    float* nw3 = nw2 + (size_t)C_ * S2_ * K_ * (S1_ + 1);

    int*   win1 = win_g;                float* dw1 = dw_g;
    int*   win2 = win_g + NBLK1 * K_;   float* dw2 = dw_g + NBLK1 * K_;
    const int* idx1 = idx_buf;
    const int* idx2 = idx_buf + (size_t)NBLK1 * B_;
    const int* idx3 = idx_buf + (size_t)(NBLK1 + NBLK2) * B_;

    prep_kernel<<<dim3(128), dim3(256), 0, stream>>>(
        x, bias1, bias2, xT, l0, l0T, out1T, out1RM, out2T, out2RM);

    // route (blocks 0..637) || w1/w2/w3 L3-prefetch (blocks 638..1657)
    route_pf_kernel<<<dim3(NBLK_ALL / 2 + NPF), dim3(256), 0, stream>>>(
        xT, cmaps1, cmaps2, cmaps3, idx_buf, w1, w2, w3);

    // layer-1 dot+fin (w1 now L3-resident)
    dotfin1_kernel<<<dim3(NBLK1), dim3(512), 0, stream>>>(
        l0T, w1, idx1, target, out1T, out1RM, win1, dw1);

    // layer-2 dot+fin || update1 first half
    mix2_kernel<<<dim3(NBLK2 + UPB1H), dim3(512), 0, stream>>>(
        out1T, w2, idx2, target, out2T, out2RM, win2, dw2,
        w1, l0, win1, dw1, nw1);

    // layer-3 fusion || update2 || update1 second half
    mix3_kernel<<<dim3(NBLK3 + UPB2 + UPB1H), dim3(512), 0, stream>>>(
        out2T, out2RM, w3, idx3, target, nw3, logits,
        w2, out1RM, win2, dw2, nw2,
        w1, l0, win1, dw1, nw1);
}

// Round 17
// 127.182 us; speedup vs baseline: 1.0332x; 1.0332x over previous
//
#include <hip/hip_runtime.h>
#include <math.h>

#define B_   256
#define IN_  512
#define C_   4
#define M_   6
#define K_   64
#define S1_  255
#define S2_  63

#define NBLK1 (C_ * S1_)                 // 1020
#define NBLK2 (C_ * S2_)                 // 252
#define NBLK3 (C_)                       // 4
#define NBLK_ALL (NBLK1 + NBLK2 + NBLK3) // 1276

#define NPF   1020                        // prefetch blocks in route launch
#define PFCAP (6 * 1024 * 1024)           // f4 elements of w1 to prefetch (~96 MB)
#define UPB1  4080                        // update1 blocks (4/tile), all in mix2
#define UPB2  504                         // update2 blocks (2/tile), in mix3

#define LMIN_ (-6.906754778648554f)
#define LMAX_ ( 6.906754778648554f)
#define LR_   0.001f
#define WCLIP_ 5.0f

typedef float v4f __attribute__((ext_vector_type(4)));

__device__ __forceinline__ float clampf(float v, float lo, float hi) {
    return fminf(fmaxf(v, lo), hi);
}

// One-time prep: xT[i][b], l0[b][i], l0T[i][b]; bias rows of out1/out2.
__global__ __launch_bounds__(256) void prep_kernel(const float* __restrict__ x,
                                                   const float* __restrict__ bias1,
                                                   const float* __restrict__ bias2,
                                                   float* __restrict__ xT,
                                                   float* __restrict__ l0,
                                                   float* __restrict__ l0T,
                                                   float* __restrict__ out1T,
                                                   float* __restrict__ out1RM,
                                                   float* __restrict__ out2T,
                                                   float* __restrict__ out2RM) {
    __shared__ float tx_[32][33];
    __shared__ float tl_[32][33];
    const int i0 = (blockIdx.x & 15) * 32;
    const int b0 = (blockIdx.x >> 4) * 32;
    const int tx = threadIdx.x & 31;
    const int ty = threadIdx.x >> 5;
#pragma unroll
    for (int r = 0; r < 4; ++r) {
        int bb = b0 + ty + 8 * r;
        int ii = i0 + tx;
        float xv = x[(size_t)bb * IN_ + ii];
        float xc = clampf(xv, 0.001f, 0.999f);
        float lv = (ii == 0) ? 0.0f : logf(xc / (1.0f - xc));
        l0[(size_t)bb * IN_ + ii] = lv;
        tx_[ty + 8 * r][tx] = xv;
        tl_[ty + 8 * r][tx] = lv;
    }
    __syncthreads();
#pragma unroll
    for (int r = 0; r < 4; ++r) {
        int ii = i0 + ty + 8 * r;
        int bb = b0 + tx;
        xT[(size_t)ii * B_ + bb]  = tx_[tx][ty + 8 * r];
        l0T[(size_t)ii * B_ + bb] = tl_[tx][ty + 8 * r];
    }
    int gid = blockIdx.x * 256 + threadIdx.x;
    if (gid < C_ * B_) {
        int c = gid >> 8, b = gid & 255;
        float b1 = bias1[c], b2 = bias2[c];
        out1T[((size_t)c * (S1_ + 1)) * B_ + b] = b1;
        out1RM[((size_t)c * B_ + b) * (S1_ + 1)] = b1;
        out2T[((size_t)c * (S2_ + 1)) * B_ + b] = b2;
        out2RM[((size_t)c * B_ + b) * (S2_ + 1)] = b2;
    }
}

// Routing (blocks [0,638)): 2 tiles/block, 4 waves x 128-k quarters (proven).
// Prefetch (blocks [638, 638+NPF)): stream the FIRST ~96 MB of w1 into L3 --
// capped to what route's idle HBM window can absorb (round-16 lesson).
__global__ __launch_bounds__(256) void route_pf_kernel(
    const float* __restrict__ xT,       // [IN][B]
    const float* __restrict__ cmaps1,
    const float* __restrict__ cmaps2,
    const float* __restrict__ cmaps3,
    int* __restrict__ idx_buf,          // [NBLK_ALL][B]
    const float* __restrict__ w1)
{
    __shared__ float sacc[3][2][M_][B_];   // 36 KB
    if ((int)blockIdx.x >= NBLK_ALL / 2) {
        const int pb = blockIdx.x - NBLK_ALL / 2;
        const int t  = pb * 256 + threadIdx.x;
        const int stride = NPF * 256;
        const float4* w1v = (const float4*)w1;
        float s = 0.0f;
        for (int i = t; i < PFCAP; i += stride) { float4 v = w1v[i]; s += v.x + v.y + v.z + v.w; }
        asm volatile("" :: "v"(s));
        return;
    }

    const int wv   = __builtin_amdgcn_readfirstlane(threadIdx.x >> 6);
    const int lane = threadIdx.x & 63;
    const int t0   = blockIdx.x * 2;

    const float* cmp[2];
#pragma unroll
    for (int u = 0; u < 2; ++u) {
        int bid = t0 + u;
        if (bid < NBLK1)              cmp[u] = cmaps1 + (size_t)bid * M_ * IN_;
        else if (bid < NBLK1 + NBLK2) cmp[u] = cmaps2 + (size_t)(bid - NBLK1) * M_ * IN_;
        else                          cmp[u] = cmaps3 + (size_t)(bid - NBLK1 - NBLK2) * M_ * IN_;
    }

    float acc[2][4][M_];
#pragma unroll
    for (int u = 0; u < 2; ++u)
#pragma unroll
        for (int jb = 0; jb < 4; ++jb)
#pragma unroll
            for (int m = 0; m < M_; ++m) acc[u][jb][m] = 0.0f;

    const int kw = wv * 128;
    for (int k0 = kw; k0 < kw + 128; k0 += 8) {
        float xv[8][4];
#pragma unroll
        for (int j = 0; j < 8; ++j)
#pragma unroll
            for (int jb = 0; jb < 4; ++jb)
                xv[j][jb] = xT[(size_t)(k0 + j) * B_ + 64 * jb + lane];
#pragma unroll
        for (int j = 0; j < 8; ++j)
#pragma unroll
            for (int u = 0; u < 2; ++u)
#pragma unroll
                for (int m = 0; m < M_; ++m) {
                    float cv = cmp[u][(size_t)m * IN_ + k0 + j];
#pragma unroll
                    for (int jb = 0; jb < 4; ++jb)
                        acc[u][jb][m] = fmaf(cv, xv[j][jb], acc[u][jb][m]);
                }
    }

    if (wv > 0) {
#pragma unroll
        for (int u = 0; u < 2; ++u)
#pragma unroll
            for (int jb = 0; jb < 4; ++jb)
#pragma unroll
                for (int m = 0; m < M_; ++m)
                    sacc[wv - 1][u][m][64 * jb + lane] = acc[u][jb][m];
    }
    __syncthreads();
    if (wv == 0) {
#pragma unroll
        for (int u = 0; u < 2; ++u)
#pragma unroll
            for (int jb = 0; jb < 4; ++jb) {
                int b = 64 * jb + lane;
                int myidx = 0;
#pragma unroll
                for (int m = 0; m < M_; ++m) {
                    float t = acc[u][jb][m] + sacc[0][u][m][b] + sacc[1][u][m][b] + sacc[2][u][m][b];
                    myidx |= (t > 0.0f) ? (1 << m) : 0;
                }
                idx_buf[(size_t)(t0 + u) * B_ + b] = myidx;
            }
    }
}

// ---- fused dot+fin per tile: 512 threads = 2 k-halves x 256 b ----
// Register-prefetch double-buffered staging (proven round 15).
template<int DIN>
__device__ __forceinline__ void dotfin_body(
    int tile,
    const float* __restrict__ lgT, long lgT_sc,
    const float* __restrict__ w,
    const int* __restrict__ idx_buf,
    const int* __restrict__ target,
    float* __restrict__ onextT,
    float* __restrict__ onextRM,
    int* __restrict__ win_g,
    float* __restrict__ dw_g,
    int S,
    float* wl, float* part_s, float* diff_s, int* win_s)
{
    constexpr int HALF = DIN / 2;
    constexpr int NR   = HALF / 64;
    const int c   = tile / S;
    const int s   = tile - c * S;
    const int tid = threadIdx.x;
    const int kh  = __builtin_amdgcn_readfirstlane(tid >> 8);
    const int b   = tid & 255;

    if (tid < K_) win_s[tid] = -1;
    const int myrow = idx_buf[(size_t)tile * B_ + b];

    const float* wp  = w + (size_t)tile * K_ * DIN + kh * HALF;
    float*       dst = wl + kh * (K_ * 65);

    int rrow[4], rq[4];
    float4 pre[4];
#pragma unroll
    for (int j = 0; j < 4; ++j) {
        int f   = b + 256 * j;
        rrow[j] = f >> 4;
        rq[j]   = (f & 15) << 2;
        pre[j]  = *(const float4*)(wp + (size_t)rrow[j] * DIN + rq[j]);
    }

    float dot = 0.0f;
#pragma unroll
    for (int r = 0; r < NR; ++r) {
#pragma unroll
        for (int j = 0; j < 4; ++j) {
            dst[rrow[j] * 65 + rq[j] + 0] = pre[j].x;
            dst[rrow[j] * 65 + rq[j] + 1] = pre[j].y;
            dst[rrow[j] * 65 + rq[j] + 2] = pre[j].z;
            dst[rrow[j] * 65 + rq[j] + 3] = pre[j].w;
        }
        if (r + 1 < NR) {
            const float* src = wp + (r + 1) * 64;
#pragma unroll
            for (int j = 0; j < 4; ++j)
                pre[j] = *(const float4*)(src + (size_t)rrow[j] * DIN + rq[j]);
        }
        __syncthreads();
        const float* lgp = lgT + (size_t)c * lgT_sc + (size_t)(kh * HALF + r * 64) * B_ + b;
        const float* wr  = dst + myrow * 65;
        for (int kk = 0; kk < 64; kk += 8) {
            float lv[8];
#pragma unroll
            for (int t = 0; t < 8; ++t) lv[t] = lgp[(size_t)(kk + t) * B_];
#pragma unroll
            for (int t = 0; t < 8; ++t) dot = fmaf(wr[kk + t], lv[t], dot);
        }
        __syncthreads();
    }
    if (kh == 1) part_s[b] = dot;
    __syncthreads();
    if (kh == 0) {
        float total = dot + part_s[b];
        float outv = clampf(total, LMIN_, LMAX_);
        onextT[((size_t)c * (S + 1) + (s + 1)) * B_ + b] = outv;
        onextRM[((size_t)c * B_ + b) * (size_t)(S + 1) + (s + 1)] = outv;
        float tg = (target[b] == c) ? 1.0f : 0.0f;
        diff_s[b] = 1.0f / (1.0f + expf(-outv)) - tg;
        atomicMax(&win_s[myrow], b);
    }
    __syncthreads();
    if (tid < K_) {
        int bw = win_s[tid];
        win_g[(size_t)tile * K_ + tid] = bw;
        dw_g[(size_t)tile * K_ + tid]  = (bw >= 0) ? LR_ * diff_s[bw] : 0.0f;
    }
}

// stream update, 512 threads, batched loads (proven round 15).
template<int DIN>
__device__ __forceinline__ void update_body(
    int ub,
    const float* __restrict__ w,
    const float* __restrict__ lgRM, long lg_sc,
    const int* __restrict__ win_g,
    const float* __restrict__ dw_g,
    float* __restrict__ nw,
    int SK)
{
    constexpr int QPR = DIN / 4;
    constexpr int QSH = (DIN == 512) ? 7 : 6;
    const int base = ub * 2048 + threadIdx.x;
    int row[4], col[4], bw[4];
    float d[4];
    float4 wv[4], lv[4];
#pragma unroll
    for (int j = 0; j < 4; ++j) {
        int Q  = base + j * 512;
        row[j] = Q >> QSH;
        col[j] = (Q & (QPR - 1)) << 2;
        wv[j]  = *(const float4*)(w + (size_t)row[j] * DIN + col[j]);
    }
#pragma unroll
    for (int j = 0; j < 4; ++j) {
        bw[j] = win_g[row[j]];
        d[j]  = dw_g[row[j]];
    }
#pragma unroll
    for (int j = 0; j < 4; ++j) {
        int safe = bw[j] < 0 ? 0 : bw[j];
        int cc   = row[j] / SK;
        lv[j] = *(const float4*)(lgRM + (size_t)cc * lg_sc + (size_t)safe * DIN + col[j]);
    }
#pragma unroll
    for (int j = 0; j < 4; ++j) {
        if (bw[j] >= 0) {
            wv[j].x = clampf(wv[j].x - d[j] * lv[j].x, -WCLIP_, WCLIP_);
            wv[j].y = clampf(wv[j].y - d[j] * lv[j].y, -WCLIP_, WCLIP_);
            wv[j].z = clampf(wv[j].z - d[j] * lv[j].z, -WCLIP_, WCLIP_);
            wv[j].w = clampf(wv[j].w - d[j] * lv[j].w, -WCLIP_, WCLIP_);
        }
        v4f o = {wv[j].x, wv[j].y, wv[j].z, wv[j].w};
        __builtin_nontemporal_store(o, (v4f*)(nw + (size_t)row[j] * DIN + col[j]));
    }
}

// Layer-1 dot+fin standalone.
__global__ __launch_bounds__(512) void dotfin1_kernel(
    const float* __restrict__ l0T,
    const float* __restrict__ w1,
    const int* __restrict__ idx1,
    const int* __restrict__ target,
    float* __restrict__ out1T, float* __restrict__ out1RM,
    int* __restrict__ win1, float* __restrict__ dw1)
{
    __shared__ float wl[2 * K_ * 65];
    __shared__ float part_s[B_];
    __shared__ float diff_s[B_];
    __shared__ int   win_s[K_];
    dotfin_body<512>(blockIdx.x, l0T, 0L, w1, idx1, target,
                     out1T, out1RM, win1, dw1, S1_, wl, part_s, diff_s, win_s);
}

// mix2: [0,NBLK2) layer-2 dot+fin; [NBLK2, NBLK2+UPB1) update1 (full).
__global__ __launch_bounds__(512) void mix2_kernel(
    const float* __restrict__ out1T,
    const float* __restrict__ w2,
    const int* __restrict__ idx2,
    const int* __restrict__ target,
    float* __restrict__ out2T, float* __restrict__ out2RM,
    int* __restrict__ win2, float* __restrict__ dw2,
    const float* __restrict__ w1,
    const float* __restrict__ l0,
    const int* __restrict__ win1, const float* __restrict__ dw1,
    float* __restrict__ nw1)
{
    __shared__ float wl[2 * K_ * 65];
    __shared__ float part_s[B_];
    __shared__ float diff_s[B_];
    __shared__ int   win_s[K_];
    if ((int)blockIdx.x < NBLK2)
        dotfin_body<256>(blockIdx.x, out1T, (long)(S1_ + 1) * B_, w2, idx2, target,
                         out2T, out2RM, win2, dw2, S2_,
                         wl, part_s, diff_s, win_s);
    else
        update_body<512>(blockIdx.x - NBLK2, w1, l0, 0L, win1, dw1, nw1, S1_ * K_);
}

// layer-3 full fusion (proven).
__device__ __forceinline__ void dotfinup3_body(
    int c,
    const float* __restrict__ lgT, long lgT_sc,
    const float* __restrict__ lgRM, long lg_sc,
    const float* __restrict__ w3,
    const int* __restrict__ idx3,
    const int* __restrict__ target,
    float* __restrict__ nw3,
    float* __restrict__ logits,
    float* wl, float* part_s, float* diff_s, float* dw_s, int* win_s)
{
    const int tid = threadIdx.x;
    const int kh  = __builtin_amdgcn_readfirstlane(tid >> 8);
    const int b   = tid & 255;
    if (tid < K_) win_s[tid] = -1;
    const int myrow = idx3[(size_t)c * B_ + b];

    const float* wp  = w3 + (size_t)c * K_ * 64 + kh * 32;
    float*       dst = wl + kh * (K_ * 33);
#pragma unroll
    for (int j = 0; j < 2; ++j) {
        int f   = b + 256 * j;
        int row = f >> 3;
        int q   = (f & 7) << 2;
        float4 v = *(const float4*)(wp + (size_t)row * 64 + q);
        dst[row * 33 + q + 0] = v.x;
        dst[row * 33 + q + 1] = v.y;
        dst[row * 33 + q + 2] = v.z;
        dst[row * 33 + q + 3] = v.w;
    }
    __syncthreads();
    const float* lgp = lgT + (size_t)c * lgT_sc + (size_t)(kh * 32) * B_ + b;
    const float* wr  = dst + myrow * 33;
    float dot = 0.0f;
    for (int kk = 0; kk < 32; kk += 8) {
        float lv[8];
#pragma unroll
        for (int t = 0; t < 8; ++t) lv[t] = lgp[(size_t)(kk + t) * B_];
#pragma unroll
        for (int t = 0; t < 8; ++t) dot = fmaf(wr[kk + t], lv[t], dot);
    }
    if (kh == 1) part_s[b] = dot;
    __syncthreads();
    if (kh == 0) {
        float total = dot + part_s[b];
        float outv = clampf(total, LMIN_, LMAX_);
        logits[(size_t)b * C_ + c] = outv;
        float tg = (target[b] == c) ? 1.0f : 0.0f;
        diff_s[b] = 1.0f / (1.0f + expf(-outv)) - tg;
        atomicMax(&win_s[myrow], b);
    }
    __syncthreads();
    if (tid < K_) dw_s[tid] = (win_s[tid] >= 0) ? LR_ * diff_s[win_s[tid]] : 0.0f;
    __syncthreads();

    const float* lgc = lgRM + (size_t)c * lg_sc;
    float* nwp = nw3 + (size_t)c * K_ * 64;
#pragma unroll
    for (int j = 0; j < 2; ++j) {
        int Q   = tid + 512 * j;
        int row = Q >> 4;
        int col = (Q & 15) << 2;
        const float* wsrc = wl + (col >> 5) * (K_ * 33) + row * 33 + (col & 31);
        float4 wv = {wsrc[0], wsrc[1], wsrc[2], wsrc[3]};
        int bw = win_s[row];
        if (bw >= 0) {
            float d = dw_s[row];
            const float4 lv = *(const float4*)(lgc + (size_t)bw * 64 + col);
            wv.x = clampf(wv.x - d * lv.x, -WCLIP_, WCLIP_);
            wv.y = clampf(wv.y - d * lv.y, -WCLIP_, WCLIP_);
            wv.z = clampf(wv.z - d * lv.z, -WCLIP_, WCLIP_);
            wv.w = clampf(wv.w - d * lv.w, -WCLIP_, WCLIP_);
        }
        v4f o = {wv.x, wv.y, wv.z, wv.w};
        __builtin_nontemporal_store(o, (v4f*)(nwp + (size_t)row * 64 + col));
    }
}

// mix3: [0,4) layer-3 fusion; [4,4+UPB2) update2.
__global__ __launch_bounds__(512) void mix3_kernel(
    const float* __restrict__ out2T,
    const float* __restrict__ out2RM,
    const float* __restrict__ w3,
    const int* __restrict__ idx3,
    const int* __restrict__ target,
    float* __restrict__ nw3,
    float* __restrict__ logits,
    const float* __restrict__ w2,
    const float* __restrict__ out1RM,
    const int* __restrict__ win2, const float* __restrict__ dw2,
    float* __restrict__ nw2)
{
    __shared__ float wl[2 * K_ * 33];
    __shared__ float part_s[B_];
    __shared__ float diff_s[B_];
    __shared__ float dw_s[K_];
    __shared__ int   win_s[K_];
    if ((int)blockIdx.x < NBLK3)
        dotfinup3_body(blockIdx.x, out2T, (long)(S2_ + 1) * B_,
                       out2RM, (long)B_ * (S2_ + 1), w3, idx3, target,
                       nw3, logits, wl, part_s, diff_s, dw_s, win_s);
    else
        update_body<256>(blockIdx.x - NBLK3, w2, out1RM, (long)B_ * (S1_ + 1),
                         win2, dw2, nw2, S2_ * K_);
}

extern "C" void kernel_launch(void* const* d_in, const int* in_sizes, int n_in,
                              void* d_out, int out_size, void* d_ws, size_t ws_size,
                              hipStream_t stream) {
    const float* x      = (const float*)d_in[0];
    const int*   target = (const int*)  d_in[1];
    const float* cmaps1 = (const float*)d_in[2];
    const float* w1     = (const float*)d_in[3];
    const float* bias1  = (const float*)d_in[4];
    const float* cmaps2 = (const float*)d_in[5];
    const float* w2     = (const float*)d_in[6];
    const float* bias2  = (const float*)d_in[7];
    const float* cmaps3 = (const float*)d_in[8];
    const float* w3     = (const float*)d_in[9];
    float* out = (float*)d_out;

    float* xT      = (float*)d_ws;
    float* l0      = xT     + (size_t)IN_ * B_;
    float* l0T     = l0     + (size_t)B_ * IN_;
    float* out1T   = l0T    + (size_t)IN_ * B_;
    float* out1RM  = out1T  + (size_t)C_ * (S1_ + 1) * B_;
    float* out2T   = out1RM + (size_t)C_ * B_ * (S1_ + 1);
    float* out2RM  = out2T  + (size_t)C_ * (S2_ + 1) * B_;
    float* dw_g    = out2RM + (size_t)C_ * B_ * (S2_ + 1);
    int*   win_g   = (int*)(dw_g + (size_t)(NBLK1 + NBLK2) * K_);
    int*   idx_buf = (int*)(win_g + (size_t)(NBLK1 + NBLK2) * K_);

    float* logits = out;
    float* nw1 = out + (size_t)B_ * C_;
    float* nw2 = nw1 + (size_t)C_ * S1_ * K_ * IN_;
    float* nw3 = nw2 + (size_t)C_ * S2_ * K_ * (S1_ + 1);

    int*   win1 = win_g;                float* dw1 = dw_g;
    int*   win2 = win_g + NBLK1 * K_;   float* dw2 = dw_g + NBLK1 * K_;
    const int* idx1 = idx_buf;
    const int* idx2 = idx_buf + (size_t)NBLK1 * B_;
    const int* idx3 = idx_buf + (size_t)(NBLK1 + NBLK2) * B_;

    prep_kernel<<<dim3(128), dim3(256), 0, stream>>>(
        x, bias1, bias2, xT, l0, l0T, out1T, out1RM, out2T, out2RM);

    // route (blocks 0..637) || capped w1 L3-prefetch (blocks 638..1657)
    route_pf_kernel<<<dim3(NBLK_ALL / 2 + NPF), dim3(256), 0, stream>>>(
        xT, cmaps1, cmaps2, cmaps3, idx_buf, w1);

    // layer-1 dot+fin (first ~75% of w1 L3-resident)
    dotfin1_kernel<<<dim3(NBLK1), dim3(512), 0, stream>>>(
        l0T, w1, idx1, target, out1T, out1RM, win1, dw1);

    // layer-2 dot+fin || update1 (full)
    mix2_kernel<<<dim3(NBLK2 + UPB1), dim3(512), 0, stream>>>(
        out1T, w2, idx2, target, out2T, out2RM, win2, dw2,
        w1, l0, win1, dw1, nw1);

    // layer-3 fusion || update2
    mix3_kernel<<<dim3(NBLK3 + UPB2), dim3(512), 0, stream>>>(
        out2T, out2RM, w3, idx3, target, nw3, logits,
        w2, out1RM, win2, dw2, nw2);
}

// Round 18
// 125.734 us; speedup vs baseline: 1.0451x; 1.0115x over previous
//
#include <hip/hip_runtime.h>
#include <math.h>

#define B_   256
#define IN_  512
#define C_   4
#define M_   6
#define K_   64
#define S1_  255
#define S2_  63

#define NBLK1 (C_ * S1_)                 // 1020
#define NBLK2 (C_ * S2_)                 // 252
#define NBLK3 (C_)                       // 4
#define NBLK_ALL (NBLK1 + NBLK2 + NBLK3) // 1276

#define UPB1  2040                        // update1 blocks (32 rows each)
#define UPB2  252                         // update2 blocks (64 rows each)

#define LMIN_ (-6.906754778648554f)
#define LMAX_ ( 6.906754778648554f)
#define LR_   0.001f
#define WCLIP_ 5.0f

typedef float v4f __attribute__((ext_vector_type(4)));

__device__ __forceinline__ float clampf(float v, float lo, float hi) {
    return fminf(fmaxf(v, lo), hi);
}

// One-time prep: xT[i][b], l0[b][i], l0T[i][b]; bias rows of out1/out2.
__global__ __launch_bounds__(256) void prep_kernel(const float* __restrict__ x,
                                                   const float* __restrict__ bias1,
                                                   const float* __restrict__ bias2,
                                                   float* __restrict__ xT,
                                                   float* __restrict__ l0,
                                                   float* __restrict__ l0T,
                                                   float* __restrict__ out1T,
                                                   float* __restrict__ out1RM,
                                                   float* __restrict__ out2T,
                                                   float* __restrict__ out2RM) {
    __shared__ float tx_[32][33];
    __shared__ float tl_[32][33];
    const int i0 = (blockIdx.x & 15) * 32;
    const int b0 = (blockIdx.x >> 4) * 32;
    const int tx = threadIdx.x & 31;
    const int ty = threadIdx.x >> 5;
#pragma unroll
    for (int r = 0; r < 4; ++r) {
        int bb = b0 + ty + 8 * r;
        int ii = i0 + tx;
        float xv = x[(size_t)bb * IN_ + ii];
        float xc = clampf(xv, 0.001f, 0.999f);
        float lv = (ii == 0) ? 0.0f : logf(xc / (1.0f - xc));
        l0[(size_t)bb * IN_ + ii] = lv;
        tx_[ty + 8 * r][tx] = xv;
        tl_[ty + 8 * r][tx] = lv;
    }
    __syncthreads();
#pragma unroll
    for (int r = 0; r < 4; ++r) {
        int ii = i0 + ty + 8 * r;
        int bb = b0 + tx;
        xT[(size_t)ii * B_ + bb]  = tx_[tx][ty + 8 * r];
        l0T[(size_t)ii * B_ + bb] = tl_[tx][ty + 8 * r];
    }
    int gid = blockIdx.x * 256 + threadIdx.x;
    if (gid < C_ * B_) {
        int c = gid >> 8, b = gid & 255;
        float b1 = bias1[c], b2 = bias2[c];
        out1T[((size_t)c * (S1_ + 1)) * B_ + b] = b1;
        out1RM[((size_t)c * B_ + b) * (S1_ + 1)] = b1;
        out2T[((size_t)c * (S2_ + 1)) * B_ + b] = b2;
        out2RM[((size_t)c * B_ + b) * (S2_ + 1)] = b2;
    }
}

// Routing: block = 2 tiles, 4 waves x 128-k quarters (proven).
__global__ __launch_bounds__(256) void route_kernel(
    const float* __restrict__ xT,       // [IN][B]
    const float* __restrict__ cmaps1,
    const float* __restrict__ cmaps2,
    const float* __restrict__ cmaps3,
    int* __restrict__ idx_buf)          // [NBLK_ALL][B]
{
    __shared__ float sacc[3][2][M_][B_];   // 36 KB
    const int wv   = __builtin_amdgcn_readfirstlane(threadIdx.x >> 6);
    const int lane = threadIdx.x & 63;
    const int t0   = blockIdx.x * 2;

    const float* cmp[2];
#pragma unroll
    for (int u = 0; u < 2; ++u) {
        int bid = t0 + u;
        if (bid < NBLK1)              cmp[u] = cmaps1 + (size_t)bid * M_ * IN_;
        else if (bid < NBLK1 + NBLK2) cmp[u] = cmaps2 + (size_t)(bid - NBLK1) * M_ * IN_;
        else                          cmp[u] = cmaps3 + (size_t)(bid - NBLK1 - NBLK2) * M_ * IN_;
    }

    float acc[2][4][M_];
#pragma unroll
    for (int u = 0; u < 2; ++u)
#pragma unroll
        for (int jb = 0; jb < 4; ++jb)
#pragma unroll
            for (int m = 0; m < M_; ++m) acc[u][jb][m] = 0.0f;

    const int kw = wv * 128;
    for (int k0 = kw; k0 < kw + 128; k0 += 8) {
        float xv[8][4];
#pragma unroll
        for (int j = 0; j < 8; ++j)
#pragma unroll
            for (int jb = 0; jb < 4; ++jb)
                xv[j][jb] = xT[(size_t)(k0 + j) * B_ + 64 * jb + lane];
#pragma unroll
        for (int j = 0; j < 8; ++j)
#pragma unroll
            for (int u = 0; u < 2; ++u)
#pragma unroll
                for (int m = 0; m < M_; ++m) {
                    float cv = cmp[u][(size_t)m * IN_ + k0 + j];
#pragma unroll
                    for (int jb = 0; jb < 4; ++jb)
                        acc[u][jb][m] = fmaf(cv, xv[j][jb], acc[u][jb][m]);
                }
    }

    if (wv > 0) {
#pragma unroll
        for (int u = 0; u < 2; ++u)
#pragma unroll
            for (int jb = 0; jb < 4; ++jb)
#pragma unroll
                for (int m = 0; m < M_; ++m)
                    sacc[wv - 1][u][m][64 * jb + lane] = acc[u][jb][m];
    }
    __syncthreads();
    if (wv == 0) {
#pragma unroll
        for (int u = 0; u < 2; ++u)
#pragma unroll
            for (int jb = 0; jb < 4; ++jb) {
                int b = 64 * jb + lane;
                int myidx = 0;
#pragma unroll
                for (int m = 0; m < M_; ++m) {
                    float t = acc[u][jb][m] + sacc[0][u][m][b] + sacc[1][u][m][b] + sacc[2][u][m][b];
                    myidx |= (t > 0.0f) ? (1 << m) : 0;
                }
                idx_buf[(size_t)(t0 + u) * B_ + b] = myidx;
            }
    }
}

// ---- fused dot+fin per tile: 512 threads = 2 k-halves x 256 b ----
// Register-prefetch double-buffered staging (proven round 15).
template<int DIN>
__device__ __forceinline__ void dotfin_body(
    int tile,
    const float* __restrict__ lgT, long lgT_sc,
    const float* __restrict__ w,
    const int* __restrict__ idx_buf,
    const int* __restrict__ target,
    float* __restrict__ onextT,
    float* __restrict__ onextRM,
    int* __restrict__ win_g,
    float* __restrict__ dw_g,
    int S,
    float* wl, float* part_s, float* diff_s, int* win_s)
{
    constexpr int HALF = DIN / 2;
    constexpr int NR   = HALF / 64;
    const int c   = tile / S;
    const int s   = tile - c * S;
    const int tid = threadIdx.x;
    const int kh  = __builtin_amdgcn_readfirstlane(tid >> 8);
    const int b   = tid & 255;

    if (tid < K_) win_s[tid] = -1;
    const int myrow = idx_buf[(size_t)tile * B_ + b];

    const float* wp  = w + (size_t)tile * K_ * DIN + kh * HALF;
    float*       dst = wl + kh * (K_ * 65);

    int rrow[4], rq[4];
    float4 pre[4];
#pragma unroll
    for (int j = 0; j < 4; ++j) {
        int f   = b + 256 * j;
        rrow[j] = f >> 4;
        rq[j]   = (f & 15) << 2;
        pre[j]  = *(const float4*)(wp + (size_t)rrow[j] * DIN + rq[j]);
    }

    float dot = 0.0f;
#pragma unroll
    for (int r = 0; r < NR; ++r) {
#pragma unroll
        for (int j = 0; j < 4; ++j) {
            dst[rrow[j] * 65 + rq[j] + 0] = pre[j].x;
            dst[rrow[j] * 65 + rq[j] + 1] = pre[j].y;
            dst[rrow[j] * 65 + rq[j] + 2] = pre[j].z;
            dst[rrow[j] * 65 + rq[j] + 3] = pre[j].w;
        }
        if (r + 1 < NR) {
            const float* src = wp + (r + 1) * 64;
#pragma unroll
            for (int j = 0; j < 4; ++j)
                pre[j] = *(const float4*)(src + (size_t)rrow[j] * DIN + rq[j]);
        }
        __syncthreads();
        const float* lgp = lgT + (size_t)c * lgT_sc + (size_t)(kh * HALF + r * 64) * B_ + b;
        const float* wr  = dst + myrow * 65;
        for (int kk = 0; kk < 64; kk += 8) {
            float lv[8];
#pragma unroll
            for (int t = 0; t < 8; ++t) lv[t] = lgp[(size_t)(kk + t) * B_];
#pragma unroll
            for (int t = 0; t < 8; ++t) dot = fmaf(wr[kk + t], lv[t], dot);
        }
        __syncthreads();
    }
    if (kh == 1) part_s[b] = dot;
    __syncthreads();
    if (kh == 0) {
        float total = dot + part_s[b];
        float outv = clampf(total, LMIN_, LMAX_);
        onextT[((size_t)c * (S + 1) + (s + 1)) * B_ + b] = outv;
        onextRM[((size_t)c * B_ + b) * (size_t)(S + 1) + (s + 1)] = outv;
        float tg = (target[b] == c) ? 1.0f : 0.0f;
        diff_s[b] = 1.0f / (1.0f + expf(-outv)) - tg;
        atomicMax(&win_s[myrow], b);
    }
    __syncthreads();
    if (tid < K_) {
        int bw = win_s[tid];
        win_g[(size_t)tile * K_ + tid] = bw;
        dw_g[(size_t)tile * K_ + tid]  = (bw >= 0) ? LR_ * diff_s[bw] : 0.0f;
    }
}

// stream update, 512 threads, 8 float4/thread (4096 f4/block): doubled ILP
// and halved block count vs round 15 (latency-bound fix).
template<int DIN>
__device__ __forceinline__ void update_body(
    int ub,
    const float* __restrict__ w,
    const float* __restrict__ lgRM, long lg_sc,
    const int* __restrict__ win_g,
    const float* __restrict__ dw_g,
    float* __restrict__ nw,
    int SK)
{
    constexpr int QPR = DIN / 4;
    constexpr int QSH = (DIN == 512) ? 7 : 6;
    const int base = ub * 4096 + threadIdx.x;
    int row[8], col[8], bw[8];
    float d[8];
    float4 wv[8], lv[8];
#pragma unroll
    for (int j = 0; j < 8; ++j) {
        int Q  = base + j * 512;
        row[j] = Q >> QSH;
        col[j] = (Q & (QPR - 1)) << 2;
        wv[j]  = *(const float4*)(w + (size_t)row[j] * DIN + col[j]);
    }
#pragma unroll
    for (int j = 0; j < 8; ++j) {
        bw[j] = win_g[row[j]];
        d[j]  = dw_g[row[j]];
    }
#pragma unroll
    for (int j = 0; j < 8; ++j) {
        int safe = bw[j] < 0 ? 0 : bw[j];
        int cc   = row[j] / SK;
        lv[j] = *(const float4*)(lgRM + (size_t)cc * lg_sc + (size_t)safe * DIN + col[j]);
    }
#pragma unroll
    for (int j = 0; j < 8; ++j) {
        if (bw[j] >= 0) {
            wv[j].x = clampf(wv[j].x - d[j] * lv[j].x, -WCLIP_, WCLIP_);
            wv[j].y = clampf(wv[j].y - d[j] * lv[j].y, -WCLIP_, WCLIP_);
            wv[j].z = clampf(wv[j].z - d[j] * lv[j].z, -WCLIP_, WCLIP_);
            wv[j].w = clampf(wv[j].w - d[j] * lv[j].w, -WCLIP_, WCLIP_);
        }
        v4f o = {wv[j].x, wv[j].y, wv[j].z, wv[j].w};
        __builtin_nontemporal_store(o, (v4f*)(nw + (size_t)row[j] * DIN + col[j]));
    }
}

// Layer-1 dot+fin standalone.
__global__ __launch_bounds__(512) void dotfin1_kernel(
    const float* __restrict__ l0T,
    const float* __restrict__ w1,
    const int* __restrict__ idx1,
    const int* __restrict__ target,
    float* __restrict__ out1T, float* __restrict__ out1RM,
    int* __restrict__ win1, float* __restrict__ dw1)
{
    __shared__ float wl[2 * K_ * 65];
    __shared__ float part_s[B_];
    __shared__ float diff_s[B_];
    __shared__ int   win_s[K_];
    dotfin_body<512>(blockIdx.x, l0T, 0L, w1, idx1, target,
                     out1T, out1RM, win1, dw1, S1_, wl, part_s, diff_s, win_s);
}

// mix2: [0,NBLK2) layer-2 dot+fin; [NBLK2, NBLK2+UPB1) update1 (full).
__global__ __launch_bounds__(512) void mix2_kernel(
    const float* __restrict__ out1T,
    const float* __restrict__ w2,
    const int* __restrict__ idx2,
    const int* __restrict__ target,
    float* __restrict__ out2T, float* __restrict__ out2RM,
    int* __restrict__ win2, float* __restrict__ dw2,
    const float* __restrict__ w1,
    const float* __restrict__ l0,
    const int* __restrict__ win1, const float* __restrict__ dw1,
    float* __restrict__ nw1)
{
    __shared__ float wl[2 * K_ * 65];
    __shared__ float part_s[B_];
    __shared__ float diff_s[B_];
    __shared__ int   win_s[K_];
    if ((int)blockIdx.x < NBLK2)
        dotfin_body<256>(blockIdx.x, out1T, (long)(S1_ + 1) * B_, w2, idx2, target,
                         out2T, out2RM, win2, dw2, S2_,
                         wl, part_s, diff_s, win_s);
    else
        update_body<512>(blockIdx.x - NBLK2, w1, l0, 0L, win1, dw1, nw1, S1_ * K_);
}

// layer-3 full fusion (proven).
__device__ __forceinline__ void dotfinup3_body(
    int c,
    const float* __restrict__ lgT, long lgT_sc,
    const float* __restrict__ lgRM, long lg_sc,
    const float* __restrict__ w3,
    const int* __restrict__ idx3,
    const int* __restrict__ target,
    float* __restrict__ nw3,
    float* __restrict__ logits,
    float* wl, float* part_s, float* diff_s, float* dw_s, int* win_s)
{
    const int tid = threadIdx.x;
    const int kh  = __builtin_amdgcn_readfirstlane(tid >> 8);
    const int b   = tid & 255;
    if (tid < K_) win_s[tid] = -1;
    const int myrow = idx3[(size_t)c * B_ + b];

    const float* wp  = w3 + (size_t)c * K_ * 64 + kh * 32;
    float*       dst = wl + kh * (K_ * 33);
#pragma unroll
    for (int j = 0; j < 2; ++j) {
        int f   = b + 256 * j;
        int row = f >> 3;
        int q   = (f & 7) << 2;
        float4 v = *(const float4*)(wp + (size_t)row * 64 + q);
        dst[row * 33 + q + 0] = v.x;
        dst[row * 33 + q + 1] = v.y;
        dst[row * 33 + q + 2] = v.z;
        dst[row * 33 + q + 3] = v.w;
    }
    __syncthreads();
    const float* lgp = lgT + (size_t)c * lgT_sc + (size_t)(kh * 32) * B_ + b;
    const float* wr  = dst + myrow * 33;
    float dot = 0.0f;
    for (int kk = 0; kk < 32; kk += 8) {
        float lv[8];
#pragma unroll
        for (int t = 0; t < 8; ++t) lv[t] = lgp[(size_t)(kk + t) * B_];
#pragma unroll
        for (int t = 0; t < 8; ++t) dot = fmaf(wr[kk + t], lv[t], dot);
    }
    if (kh == 1) part_s[b] = dot;
    __syncthreads();
    if (kh == 0) {
        float total = dot + part_s[b];
        float outv = clampf(total, LMIN_, LMAX_);
        logits[(size_t)b * C_ + c] = outv;
        float tg = (target[b] == c) ? 1.0f : 0.0f;
        diff_s[b] = 1.0f / (1.0f + expf(-outv)) - tg;
        atomicMax(&win_s[myrow], b);
    }
    __syncthreads();
    if (tid < K_) dw_s[tid] = (win_s[tid] >= 0) ? LR_ * diff_s[win_s[tid]] : 0.0f;
    __syncthreads();

    const float* lgc = lgRM + (size_t)c * lg_sc;
    float* nwp = nw3 + (size_t)c * K_ * 64;
#pragma unroll
    for (int j = 0; j < 2; ++j) {
        int Q   = tid + 512 * j;
        int row = Q >> 4;
        int col = (Q & 15) << 2;
        const float* wsrc = wl + (col >> 5) * (K_ * 33) + row * 33 + (col & 31);
        float4 wv = {wsrc[0], wsrc[1], wsrc[2], wsrc[3]};
        int bw = win_s[row];
        if (bw >= 0) {
            float d = dw_s[row];
            const float4 lv = *(const float4*)(lgc + (size_t)bw * 64 + col);
            wv.x = clampf(wv.x - d * lv.x, -WCLIP_, WCLIP_);
            wv.y = clampf(wv.y - d * lv.y, -WCLIP_, WCLIP_);
            wv.z = clampf(wv.z - d * lv.z, -WCLIP_, WCLIP_);
            wv.w = clampf(wv.w - d * lv.w, -WCLIP_, WCLIP_);
        }
        v4f o = {wv.x, wv.y, wv.z, wv.w};
        __builtin_nontemporal_store(o, (v4f*)(nwp + (size_t)row * 64 + col));
    }
}

// mix3: [0,4) layer-3 fusion; [4,4+UPB2) update2.
__global__ __launch_bounds__(512) void mix3_kernel(
    const float* __restrict__ out2T,
    const float* __restrict__ out2RM,
    const float* __restrict__ w3,
    const int* __restrict__ idx3,
    const int* __restrict__ target,
    float* __restrict__ nw3,
    float* __restrict__ logits,
    const float* __restrict__ w2,
    const float* __restrict__ out1RM,
    const int* __restrict__ win2, const float* __restrict__ dw2,
    float* __restrict__ nw2)
{
    __shared__ float wl[2 * K_ * 33];
    __shared__ float part_s[B_];
    __shared__ float diff_s[B_];
    __shared__ float dw_s[K_];
    __shared__ int   win_s[K_];
    if ((int)blockIdx.x < NBLK3)
        dotfinup3_body(blockIdx.x, out2T, (long)(S2_ + 1) * B_,
                       out2RM, (long)B_ * (S2_ + 1), w3, idx3, target,
                       nw3, logits, wl, part_s, diff_s, dw_s, win_s);
    else
        update_body<256>(blockIdx.x - NBLK3, w2, out1RM, (long)B_ * (S1_ + 1),
                         win2, dw2, nw2, S2_ * K_);
}

extern "C" void kernel_launch(void* const* d_in, const int* in_sizes, int n_in,
                              void* d_out, int out_size, void* d_ws, size_t ws_size,
                              hipStream_t stream) {
    const float* x      = (const float*)d_in[0];
    const int*   target = (const int*)  d_in[1];
    const float* cmaps1 = (const float*)d_in[2];
    const float* w1     = (const float*)d_in[3];
    const float* bias1  = (const float*)d_in[4];
    const float* cmaps2 = (const float*)d_in[5];
    const float* w2     = (const float*)d_in[6];
    const float* bias2  = (const float*)d_in[7];
    const float* cmaps3 = (const float*)d_in[8];
    const float* w3     = (const float*)d_in[9];
    float* out = (float*)d_out;

    float* xT      = (float*)d_ws;
    float* l0      = xT     + (size_t)IN_ * B_;
    float* l0T     = l0     + (size_t)B_ * IN_;
    float* out1T   = l0T    + (size_t)IN_ * B_;
    float* out1RM  = out1T  + (size_t)C_ * (S1_ + 1) * B_;
    float* out2T   = out1RM + (size_t)C_ * B_ * (S1_ + 1);
    float* out2RM  = out2T  + (size_t)C_ * (S2_ + 1) * B_;
    float* dw_g    = out2RM + (size_t)C_ * B_ * (S2_ + 1);
    int*   win_g   = (int*)(dw_g + (size_t)(NBLK1 + NBLK2) * K_);
    int*   idx_buf = (int*)(win_g + (size_t)(NBLK1 + NBLK2) * K_);

    float* logits = out;
    float* nw1 = out + (size_t)B_ * C_;
    float* nw2 = nw1 + (size_t)C_ * S1_ * K_ * IN_;
    float* nw3 = nw2 + (size_t)C_ * S2_ * K_ * (S1_ + 1);

    int*   win1 = win_g;                float* dw1 = dw_g;
    int*   win2 = win_g + NBLK1 * K_;   float* dw2 = dw_g + NBLK1 * K_;
    const int* idx1 = idx_buf;
    const int* idx2 = idx_buf + (size_t)NBLK1 * B_;
    const int* idx3 = idx_buf + (size_t)(NBLK1 + NBLK2) * B_;

    prep_kernel<<<dim3(128), dim3(256), 0, stream>>>(
        x, bias1, bias2, xT, l0, l0T, out1T, out1RM, out2T, out2RM);

    route_kernel<<<dim3(NBLK_ALL / 2), dim3(256), 0, stream>>>(
        xT, cmaps1, cmaps2, cmaps3, idx_buf);

    // layer-1 dot+fin
    dotfin1_kernel<<<dim3(NBLK1), dim3(512), 0, stream>>>(
        l0T, w1, idx1, target, out1T, out1RM, win1, dw1);

    // layer-2 dot+fin || update1 (full, 8 f4/thread)
    mix2_kernel<<<dim3(NBLK2 + UPB1), dim3(512), 0, stream>>>(
        out1T, w2, idx2, target, out2T, out2RM, win2, dw2,
        w1, l0, win1, dw1, nw1);

    // layer-3 fusion || update2 (8 f4/thread)
    mix3_kernel<<<dim3(NBLK3 + UPB2), dim3(512), 0, stream>>>(
        out2T, out2RM, w3, idx3, target, nw3, logits,
        w2, out1RM, win2, dw2, nw2);
}